// Round 1
// baseline (91695.319 us; speedup 1.0000x reference)
//
#include <hip/hip_runtime.h>

#define TT   512
#define NBOX 30
#define XDIM 4096
#define HDIM 512
#define HCC  32

#define M1 (TT*31)     // 15872
#define N1 HDIM        // 512
#define K1 XDIM        // 4096
#define M2 (TT*NBOX)   // 15360
#define N2 (3*HDIM)    // 1536
#define K2 (2*HDIM)    // 1024

#define HSTR 516       // LDS row stride for h (512 + 4): 16B-aligned rows, bank spread

__device__ __forceinline__ float sigmf_(float x) { return 1.0f / (1.0f + __expf(-x)); }

// ---------------------------------------------------------------------------
// GEMM 1: xv = relu(flow @ W_phi + b_phi)   [15872,4096]x[4096,512]
// 64x64 tile, BK=16, 256 threads, 4x4 per thread, f32
// ---------------------------------------------------------------------------
__global__ __launch_bounds__(256) void gemm_phi(const float* __restrict__ A,
                                                const float* __restrict__ B,
                                                const float* __restrict__ bias,
                                                float* __restrict__ C) {
    __shared__ float As[16][68];
    __shared__ float Bs[16][68];
    const int tid = threadIdx.x;
    const int m0 = blockIdx.x * 64;
    const int n0 = blockIdx.y * 64;
    const int am = tid >> 2, ak = (tid & 3) << 2;      // A loader: row, k-quad
    const int bk = tid >> 4, bn = (tid & 15) << 2;     // B loader: k-row, n-quad
    const int ty = tid >> 4, tx = tid & 15;            // compute mapping
    float acc[4][4] = {};
    for (int k0 = 0; k0 < K1; k0 += 16) {
        const float4 av = *(const float4*)&A[(size_t)(m0 + am) * K1 + k0 + ak];
        const float4 bv = *(const float4*)&B[(size_t)(k0 + bk) * N1 + n0 + bn];
        __syncthreads();
        As[ak + 0][am] = av.x; As[ak + 1][am] = av.y; As[ak + 2][am] = av.z; As[ak + 3][am] = av.w;
        *(float4*)&Bs[bk][bn] = bv;
        __syncthreads();
#pragma unroll
        for (int kk = 0; kk < 16; ++kk) {
            const float4 a = *(const float4*)&As[kk][ty << 2];
            const float4 b = *(const float4*)&Bs[kk][tx << 2];
            const float ar[4] = {a.x, a.y, a.z, a.w};
            const float br[4] = {b.x, b.y, b.z, b.w};
#pragma unroll
            for (int i = 0; i < 4; ++i)
#pragma unroll
                for (int j = 0; j < 4; ++j) acc[i][j] = fmaf(ar[i], br[j], acc[i][j]);
        }
    }
    const float4 bsv = *(const float4*)&bias[n0 + (tx << 2)];
    const float bb[4] = {bsv.x, bsv.y, bsv.z, bsv.w};
#pragma unroll
    for (int i = 0; i < 4; ++i) {
        const int m = m0 + (ty << 2) + i;
        float4 o;
        o.x = fmaxf(acc[i][0] + bb[0], 0.f);
        o.y = fmaxf(acc[i][1] + bb[1], 0.f);
        o.z = fmaxf(acc[i][2] + bb[2], 0.f);
        o.w = fmaxf(acc[i][3] + bb[3], 0.f);
        *(float4*)&C[(size_t)m * N1 + n0 + (tx << 2)] = o;
    }
}

// ---------------------------------------------------------------------------
// GEMM 2: gi0 = x_t @ Wih0^T + bih0, x_t = concat(xv[t,1+j], xv[t,0])
// [15360,1024] x [1024->1536],  B[k][n] = Wih0[n][k]
// ---------------------------------------------------------------------------
__global__ __launch_bounds__(256) void gemm_gi0(const float* __restrict__ xv,
                                                const float* __restrict__ Wih0,
                                                const float* __restrict__ bih0,
                                                float* __restrict__ C) {
    __shared__ float As[16][68];
    __shared__ float Bs[16][68];
    const int tid = threadIdx.x;
    const int m0 = blockIdx.x * 64;
    const int n0 = blockIdx.y * 64;
    const int am = tid >> 2, ak = (tid & 3) << 2;
    const int bn_ = tid >> 2, bkq = (tid & 3) << 2;    // B loader: n-row, k-quad (transposed store)
    const int ty = tid >> 4, tx = tid & 15;
    const int r = m0 + am;
    const int t = r / 30;
    const int j = r - t * 30;
    const float* rowTrk = xv + ((size_t)(t * 31 + 1 + j) << 9);
    const float* rowImg = xv + ((size_t)(t * 31) << 9);
    float acc[4][4] = {};
    for (int k0 = 0; k0 < K2; k0 += 16) {
        const int kg = k0 + ak;
        const float4 av = (kg < 512) ? *(const float4*)&rowTrk[kg]
                                     : *(const float4*)&rowImg[kg - 512];
        const float4 wv = *(const float4*)&Wih0[(size_t)(n0 + bn_) * K2 + k0 + bkq];
        __syncthreads();
        As[ak + 0][am] = av.x; As[ak + 1][am] = av.y; As[ak + 2][am] = av.z; As[ak + 3][am] = av.w;
        Bs[bkq + 0][bn_] = wv.x; Bs[bkq + 1][bn_] = wv.y; Bs[bkq + 2][bn_] = wv.z; Bs[bkq + 3][bn_] = wv.w;
        __syncthreads();
#pragma unroll
        for (int kk = 0; kk < 16; ++kk) {
            const float4 a = *(const float4*)&As[kk][ty << 2];
            const float4 b = *(const float4*)&Bs[kk][tx << 2];
            const float ar[4] = {a.x, a.y, a.z, a.w};
            const float br[4] = {b.x, b.y, b.z, b.w};
#pragma unroll
            for (int i = 0; i < 4; ++i)
#pragma unroll
                for (int jq = 0; jq < 4; ++jq) acc[i][jq] = fmaf(ar[i], br[jq], acc[i][jq]);
        }
    }
    const float4 bsv = *(const float4*)&bih0[n0 + (tx << 2)];
    const float bb[4] = {bsv.x, bsv.y, bsv.z, bsv.w};
#pragma unroll
    for (int i = 0; i < 4; ++i) {
        const int m = m0 + (ty << 2) + i;
        float4 o;
        o.x = acc[i][0] + bb[0];
        o.y = acc[i][1] + bb[1];
        o.z = acc[i][2] + bb[2];
        o.w = acc[i][3] + bb[3];
        *(float4*)&C[(size_t)m * N2 + n0 + (tx << 2)] = o;
    }
}

// ---------------------------------------------------------------------------
// gic = cor @ Wihc^T + bihc   (tiny, fully parallel over t,j,g)
// ---------------------------------------------------------------------------
__global__ __launch_bounds__(256) void gic_kernel(const int* __restrict__ y,
                                                  const float* __restrict__ Wihc,
                                                  const float* __restrict__ bihc,
                                                  float* __restrict__ gic) {
    const int idx = blockIdx.x * 256 + threadIdx.x;
    if (idx >= M2 * 96) return;
    const int g = idx % 96;
    const int tj = idx / 96;
    const int* yb = y + (size_t)tj * 6;
    const float c0 = (float)yb[1] * (1.f / 1080.f);
    const float c1 = (float)yb[2] * (1.f / 720.f);
    const float c2 = (float)yb[3] * (1.f / 1080.f);
    const float c3 = (float)yb[4] * (1.f / 720.f);
    gic[idx] = bihc[g] + c0 * Wihc[g * 4 + 0] + c1 * Wihc[g * 4 + 1]
                       + c2 * Wihc[g * 4 + 2] + c3 * Wihc[g * 4 + 3];
}

// ---------------------------------------------------------------------------
// init: zero attention scales (both parities) + loss accumulator
// ---------------------------------------------------------------------------
__global__ void init_k(float* s0, float* s1, float* sc, float* lossAcc) {
    const int tid = threadIdx.x;
    if (tid < 64) s0[tid] = 0.f;
    else if (tid < 128) s1[tid - 64] = 0.f;
    else if (tid < 192) sc[tid - 128] = 0.f;
    else if (tid == 192) *lossAcc = 0.f;
}

__global__ void fin_k(const float* lossAcc, float* out) { out[0] = *lossAcc; }

// ---------------------------------------------------------------------------
// Sequential step, phase 2: h0_n combine (redundant per-WG, LDS), then
// [Z0(t), gi1(t)] = h0_n @ [Whh0; Wih1]^T.  WG96: attention a0 + store h0_n.
// WG97: coordinate GRU chain (hc_n, Zc, ac).
// ---------------------------------------------------------------------------
struct SeqP {
    const float *gi0_t, *Whh0, *Wih1, *bhh0, *bih1;
    const float *Z0r; float *Z0w; const float *h0r; float *h0w;
    const float *s0r; float *s0w; float *gi1;
    const float *gic_t, *Whhc, *bhhc;
    const float *Zcr; float *Zcw; const float *hcr; float *hcw;
    const float *scr; float *scw;
    const float *wa, *wac; const int *y_t;
};

__global__ __launch_bounds__(256) void seq_p2(SeqP p) {
    __shared__ float h[NBOX * HSTR];
    __shared__ float red[256];
    const int tid = threadIdx.x;
    const int wg = blockIdx.x;

    if (wg <= 96) {
        for (int idx = tid; idx < NBOX * HDIM; idx += 256) {
            const int j = idx >> 9, c = idx & 511;
            const float s = p.s0r[j];
            const float* gi = p.gi0_t + j * 1536;
            const float* zp = p.Z0r + j * 1536;
            const float gr = gi[c] + s * zp[c] + p.bhh0[c];
            const float gz = gi[512 + c] + s * zp[512 + c] + p.bhh0[512 + c];
            const float gin = gi[1024 + c];
            const float ghn = s * zp[1024 + c] + p.bhh0[1024 + c];
            const float hv = s * p.h0r[(j << 9) + c];
            const float r = sigmf_(gr), z = sigmf_(gz);
            const float n = tanhf(gin + r * ghn);
            h[j * HSTR + c] = (1.f - z) * n + z * hv;
        }
        __syncthreads();
    }

    if (wg < 96) {
        const int n0 = wg * 32;
        const float* W; float* outp; const float* bias; int nc;
        if (n0 < 1536) { W = p.Whh0; outp = p.Z0w; bias = nullptr; nc = n0; }
        else { W = p.Wih1; outp = p.gi1; bias = p.bih1; nc = n0 - 1536; }
        if (tid < 240) {
            const int j = tid >> 3, nq = (tid & 7) << 2;
            const float* hr = &h[j * HSTR];
            const float* w0 = W + (size_t)(nc + nq + 0) * 512;
            const float* w1 = W + (size_t)(nc + nq + 1) * 512;
            const float* w2 = W + (size_t)(nc + nq + 2) * 512;
            const float* w3 = W + (size_t)(nc + nq + 3) * 512;
            float a0 = 0, a1 = 0, a2 = 0, a3 = 0;
            for (int c = 0; c < 512; c += 4) {
                const float4 hv = *(const float4*)&hr[c];
                const float4 x0 = *(const float4*)&w0[c];
                const float4 x1 = *(const float4*)&w1[c];
                const float4 x2 = *(const float4*)&w2[c];
                const float4 x3 = *(const float4*)&w3[c];
                a0 += hv.x * x0.x + hv.y * x0.y + hv.z * x0.z + hv.w * x0.w;
                a1 += hv.x * x1.x + hv.y * x1.y + hv.z * x1.z + hv.w * x1.w;
                a2 += hv.x * x2.x + hv.y * x2.y + hv.z * x2.z + hv.w * x2.w;
                a3 += hv.x * x3.x + hv.y * x3.y + hv.z * x3.z + hv.w * x3.w;
            }
            if (bias) { a0 += bias[nc + nq]; a1 += bias[nc + nq + 1]; a2 += bias[nc + nq + 2]; a3 += bias[nc + nq + 3]; }
            float* orow = outp + j * 1536 + nc + nq;
            orow[0] = a0; orow[1] = a1; orow[2] = a2; orow[3] = a3;
        }
    } else if (wg == 96) {
        float part = 0.f;
        if (tid < 240) {
            const int j = tid >> 3, c0 = (tid & 7) << 6;
            const float* hr = &h[j * HSTR];
            for (int c = c0; c < c0 + 64; ++c) part += tanhf(hr[c]) * p.wa[c];
        }
        red[tid] = part;
        __syncthreads();
        float sj = 0.f;
        if (tid < 30) for (int i = 0; i < 8; ++i) sj += red[(tid << 3) + i];
        __syncthreads();
        if (tid < 30) red[tid] = sj;
        __syncthreads();
        if (tid == 0) {
            float mx = -1e30f;
            for (int j = 0; j < 30; ++j) if (p.y_t[j * 6] != 0 && red[j] > mx) mx = red[j];
            float e[30]; float sum = 0.f;
            for (int j = 0; j < 30; ++j) { e[j] = (p.y_t[j * 6] != 0) ? __expf(red[j] - mx) : 0.f; sum += e[j]; }
            const float inv = 1.f / fmaxf(sum, 1e-9f);
            for (int j = 0; j < 30; ++j) p.s0w[j] = e[j] * inv;
        }
        for (int idx = tid; idx < NBOX * HDIM; idx += 256) {
            const int j = idx >> 9, c = idx & 511;
            p.h0w[idx] = h[j * HSTR + c];
        }
    } else {
        // wg == 97: coordinate GRU
        for (int idx = tid; idx < NBOX * HCC; idx += 256) {
            const int j = idx >> 5, c = idx & 31;
            const float s = p.scr[j];
            const float* gi = p.gic_t + j * 96;
            const float* zp = p.Zcr + j * 96;
            const float gr = gi[c] + s * zp[c] + p.bhhc[c];
            const float gz = gi[32 + c] + s * zp[32 + c] + p.bhhc[32 + c];
            const float gin = gi[64 + c];
            const float ghn = s * zp[64 + c] + p.bhhc[64 + c];
            const float hv = s * p.hcr[(j << 5) + c];
            const float r = sigmf_(gr), z = sigmf_(gz);
            const float n = tanhf(gin + r * ghn);
            const float hn = (1.f - z) * n + z * hv;
            h[idx] = hn;
            p.hcw[idx] = hn;
        }
        __syncthreads();
        for (int idx = tid; idx < NBOX * 96; idx += 256) {
            const int j = idx / 96, g = idx - j * 96;
            const float* hr = &h[j << 5];
            const float* wr = p.Whhc + g * 32;
            float a = 0.f;
            for (int c = 0; c < 32; ++c) a += hr[c] * wr[c];
            p.Zcw[j * 96 + g] = a;
        }
        float part = 0.f;
        if (tid < 30) {
            const float* hr = &h[tid << 5];
            for (int c = 0; c < 32; ++c) part += tanhf(hr[c]) * p.wac[c];
        }
        __syncthreads();
        if (tid < 30) red[tid] = part;
        __syncthreads();
        if (tid == 0) {
            float mx = -1e30f;
            for (int j = 0; j < 30; ++j) if (p.y_t[j * 6] != 0 && red[j] > mx) mx = red[j];
            float e[30]; float sum = 0.f;
            for (int j = 0; j < 30; ++j) { e[j] = (p.y_t[j * 6] != 0) ? __expf(red[j] - mx) : 0.f; sum += e[j]; }
            const float inv = 1.f / fmaxf(sum, 1e-9f);
            for (int j = 0; j < 30; ++j) p.scw[j] = e[j] * inv;
        }
    }
}

// ---------------------------------------------------------------------------
// Sequential step, phase 3: h1_n combine, Z1(t) = h1_n @ Whh1^T (WG 0..47),
// classifier + loss + outs per track (WG 48..77), attention a1 (WG 78).
// ---------------------------------------------------------------------------
struct SeqQ {
    const float *gi1, *Whh1, *bhh1;
    const float *Z1r; float *Z1w; const float *h1r; float *h1w;
    const float *s1r; float *s1w;
    const float *hcn_p;
    const float *W1, *b1, *W2, *b2, *wa;
    const int *y_t;
    float *outs_t;
    float *lossAcc;
};

__global__ __launch_bounds__(256) void seq_p3(SeqQ q) {
    __shared__ float h[NBOX * HSTR];
    __shared__ float red[256];
    const int tid = threadIdx.x;
    const int wg = blockIdx.x;

    for (int idx = tid; idx < NBOX * HDIM; idx += 256) {
        const int j = idx >> 9, c = idx & 511;
        const float s = q.s1r[j];
        const float* gi = q.gi1 + j * 1536;
        const float* zp = q.Z1r + j * 1536;
        const float gr = gi[c] + s * zp[c] + q.bhh1[c];
        const float gz = gi[512 + c] + s * zp[512 + c] + q.bhh1[512 + c];
        const float gin = gi[1024 + c];
        const float ghn = s * zp[1024 + c] + q.bhh1[1024 + c];
        const float hv = s * q.h1r[(j << 9) + c];
        const float r = sigmf_(gr), z = sigmf_(gz);
        const float n = tanhf(gin + r * ghn);
        h[j * HSTR + c] = (1.f - z) * n + z * hv;
    }
    __syncthreads();

    if (wg < 48) {
        const int n0 = wg * 32;
        if (tid < 240) {
            const int j = tid >> 3, nq = (tid & 7) << 2;
            const float* hr = &h[j * HSTR];
            const float* w0 = q.Whh1 + (size_t)(n0 + nq + 0) * 512;
            const float* w1 = q.Whh1 + (size_t)(n0 + nq + 1) * 512;
            const float* w2 = q.Whh1 + (size_t)(n0 + nq + 2) * 512;
            const float* w3 = q.Whh1 + (size_t)(n0 + nq + 3) * 512;
            float a0 = 0, a1 = 0, a2 = 0, a3 = 0;
            for (int c = 0; c < 512; c += 4) {
                const float4 hv = *(const float4*)&hr[c];
                const float4 x0 = *(const float4*)&w0[c];
                const float4 x1 = *(const float4*)&w1[c];
                const float4 x2 = *(const float4*)&w2[c];
                const float4 x3 = *(const float4*)&w3[c];
                a0 += hv.x * x0.x + hv.y * x0.y + hv.z * x0.z + hv.w * x0.w;
                a1 += hv.x * x1.x + hv.y * x1.y + hv.z * x1.z + hv.w * x1.w;
                a2 += hv.x * x2.x + hv.y * x2.y + hv.z * x2.z + hv.w * x2.w;
                a3 += hv.x * x3.x + hv.y * x3.y + hv.z * x3.z + hv.w * x3.w;
            }
            float* orow = q.Z1w + j * 1536 + n0 + nq;
            orow[0] = a0; orow[1] = a1; orow[2] = a2; orow[3] = a3;
        }
    } else if (wg < 78) {
        const int j = wg - 48;
        const bool pres = (q.y_t[j * 6] != 0);
        const float pm = pres ? 1.f : 0.f;
        const float* hr = &h[j * HSTR];
        float acc = q.b1[tid];
#pragma unroll 4
        for (int c = 0; c < 512; ++c) acc = fmaf(hr[c], q.W1[c * 256 + tid], acc);
        const float* hcv = q.hcn_p + j * 32;
#pragma unroll
        for (int c = 0; c < 32; ++c) acc = fmaf(hcv[c], q.W1[(512 + c) * 256 + tid], acc);
        const float u = fmaxf(acc, 0.f);
        float p0 = u * q.W2[tid * 2], p1 = u * q.W2[tid * 2 + 1];
#pragma unroll
        for (int off = 32; off > 0; off >>= 1) {
            p0 += __shfl_down(p0, off, 64);
            p1 += __shfl_down(p1, off, 64);
        }
        if ((tid & 63) == 0) { red[(tid >> 6) * 2] = p0; red[(tid >> 6) * 2 + 1] = p1; }
        __syncthreads();
        if (tid == 0) {
            const float o0 = q.b2[0] + red[0] + red[2] + red[4] + red[6];
            const float o1 = q.b2[1] + red[1] + red[3] + red[5] + red[7];
            const int tgt = q.y_t[j * 6 + 5];
            const float m = fmaxf(o0, o1);
            const float lse = m + __logf(__expf(o0 - m) + __expf(o1 - m));
            const float lp = ((tgt == 0) ? o0 : o1) - lse;
            if (pres) atomicAdd(q.lossAcc, -lp);
            q.outs_t[j * 2] = o0 * pm;
            q.outs_t[j * 2 + 1] = o1 * pm;
        }
    } else {
        // wg == 78: attention on h1_n, store h1_n + scale1
        float part = 0.f;
        if (tid < 240) {
            const int j = tid >> 3, c0 = (tid & 7) << 6;
            const float* hr = &h[j * HSTR];
            for (int c = c0; c < c0 + 64; ++c) part += tanhf(hr[c]) * q.wa[c];
        }
        red[tid] = part;
        __syncthreads();
        float sj = 0.f;
        if (tid < 30) for (int i = 0; i < 8; ++i) sj += red[(tid << 3) + i];
        __syncthreads();
        if (tid < 30) red[tid] = sj;
        __syncthreads();
        if (tid == 0) {
            float mx = -1e30f;
            for (int j = 0; j < 30; ++j) if (q.y_t[j * 6] != 0 && red[j] > mx) mx = red[j];
            float e[30]; float sum = 0.f;
            for (int j = 0; j < 30; ++j) { e[j] = (q.y_t[j * 6] != 0) ? __expf(red[j] - mx) : 0.f; sum += e[j]; }
            const float inv = 1.f / fmaxf(sum, 1e-9f);
            for (int j = 0; j < 30; ++j) q.s1w[j] = e[j] * inv;
        }
        for (int idx = tid; idx < NBOX * HDIM; idx += 256) {
            const int j = idx >> 9, c = idx & 511;
            q.h1w[idx] = h[j * HSTR + c];
        }
    }
}

// ---------------------------------------------------------------------------
extern "C" void kernel_launch(void* const* d_in, const int* in_sizes, int n_in,
                              void* d_out, int out_size, void* d_ws, size_t ws_size,
                              hipStream_t stream) {
    (void)in_sizes; (void)n_in; (void)out_size; (void)ws_size;
    const int*   y    = (const int*)d_in[1];
    const float* flow = (const float*)d_in[2];
    const float* W_phi = (const float*)d_in[3];
    const float* b_phi = (const float*)d_in[4];
    const float* Wih0 = (const float*)d_in[5];
    const float* Whh0 = (const float*)d_in[6];
    const float* bih0 = (const float*)d_in[7];
    const float* bhh0 = (const float*)d_in[8];
    const float* Wih1 = (const float*)d_in[9];
    const float* Whh1 = (const float*)d_in[10];
    const float* bih1 = (const float*)d_in[11];
    const float* bhh1 = (const float*)d_in[12];
    const float* Wihc = (const float*)d_in[13];
    const float* Whhc = (const float*)d_in[14];
    const float* bihc = (const float*)d_in[15];
    const float* bhhc = (const float*)d_in[16];
    const float* W1   = (const float*)d_in[17];
    const float* b1   = (const float*)d_in[18];
    const float* W2   = (const float*)d_in[19];
    const float* b2   = (const float*)d_in[20];
    const float* wa   = (const float*)d_in[21];
    const float* wac  = (const float*)d_in[22];
    float* out = (float*)d_out;

    float* ws = (float*)d_ws;
    float* xv   = ws;  ws += (size_t)M1 * N1;       // 8,126,464
    float* gi0  = ws;  ws += (size_t)M2 * N2;       // 23,592,960
    float* gic  = ws;  ws += (size_t)M2 * 96;       // 1,474,560
    float* Z0   = ws;  ws += 2 * NBOX * 1536;
    float* Z1   = ws;  ws += 2 * NBOX * 1536;
    float* Zc   = ws;  ws += 2 * NBOX * 96;
    float* gi1  = ws;  ws += NBOX * 1536;
    float* h0n  = ws;  ws += 2 * NBOX * 512;
    float* h1n  = ws;  ws += 2 * NBOX * 512;
    float* hcn  = ws;  ws += 2 * NBOX * 32;
    float* s0   = ws;  ws += 64;
    float* s1   = ws;  ws += 64;
    float* sc   = ws;  ws += 64;
    float* lossAcc = ws; ws += 1;

    hipLaunchKernelGGL(init_k, dim3(1), dim3(256), 0, stream, s0, s1, sc, lossAcc);
    hipLaunchKernelGGL(gemm_phi, dim3(M1 / 64, N1 / 64), dim3(256), 0, stream, flow, W_phi, b_phi, xv);
    hipLaunchKernelGGL(gemm_gi0, dim3(M2 / 64, N2 / 64), dim3(256), 0, stream, xv, Wih0, bih0, gi0);
    hipLaunchKernelGGL(gic_kernel, dim3((M2 * 96 + 255) / 256), dim3(256), 0, stream, y, Wihc, bihc, gic);

    for (int t = 0; t < TT; ++t) {
        const int pw = t & 1, pr = pw ^ 1;
        SeqP p;
        p.gi0_t = gi0 + (size_t)t * NBOX * 1536;
        p.Whh0 = Whh0; p.Wih1 = Wih1; p.bhh0 = bhh0; p.bih1 = bih1;
        p.Z0r = Z0 + pr * NBOX * 1536; p.Z0w = Z0 + pw * NBOX * 1536;
        p.h0r = h0n + pr * NBOX * 512; p.h0w = h0n + pw * NBOX * 512;
        p.s0r = s0 + pr * 32; p.s0w = s0 + pw * 32;
        p.gi1 = gi1;
        p.gic_t = gic + (size_t)t * NBOX * 96;
        p.Whhc = Whhc; p.bhhc = bhhc;
        p.Zcr = Zc + pr * NBOX * 96; p.Zcw = Zc + pw * NBOX * 96;
        p.hcr = hcn + pr * NBOX * 32; p.hcw = hcn + pw * NBOX * 32;
        p.scr = sc + pr * 32; p.scw = sc + pw * 32;
        p.wa = wa; p.wac = wac;
        p.y_t = y + (size_t)t * NBOX * 6;
        hipLaunchKernelGGL(seq_p2, dim3(98), dim3(256), 0, stream, p);

        SeqQ q;
        q.gi1 = gi1; q.Whh1 = Whh1; q.bhh1 = bhh1;
        q.Z1r = Z1 + pr * NBOX * 1536; q.Z1w = Z1 + pw * NBOX * 1536;
        q.h1r = h1n + pr * NBOX * 512; q.h1w = h1n + pw * NBOX * 512;
        q.s1r = s1 + pr * 32; q.s1w = s1 + pw * 32;
        q.hcn_p = hcn + pw * NBOX * 32;
        q.W1 = W1; q.b1 = b1; q.W2 = W2; q.b2 = b2; q.wa = wa;
        q.y_t = y + (size_t)t * NBOX * 6;
        q.outs_t = out + 1 + (size_t)t * NBOX * 2;
        q.lossAcc = lossAcc;
        hipLaunchKernelGGL(seq_p3, dim3(79), dim3(256), 0, stream, q);
    }
    hipLaunchKernelGGL(fin_k, dim3(1), dim3(1), 0, stream, lossAcc, out);
}

// Round 2
// 55153.149 us; speedup vs baseline: 1.6626x; 1.6626x over previous
//
#include <hip/hip_runtime.h>

#define TT   512
#define NBOX 30
#define HDIM 512
#define M1 (TT*31)     // 15872
#define N1 HDIM        // 512
#define K1 4096
#define M2 (TT*NBOX)   // 15360
#define N2 (3*HDIM)    // 1536
#define K2 (2*HDIM)    // 1024
#define NWG 256

__device__ __forceinline__ float4 ld4(const float* p) { return *(const float4*)p; }
__device__ __forceinline__ float dot4(float4 a, float4 b) { return a.x*b.x + a.y*b.y + a.z*b.z + a.w*b.w; }
__device__ __forceinline__ float sigf(float x) { return 1.f / (1.f + __expf(-x)); }
__device__ __forceinline__ float thf(float x)  { return 1.f - 2.f / (1.f + __expf(2.f*x)); }

// ---------------------------------------------------------------------------
// GEMM 1: xv = relu(flow @ W_phi + b_phi)   (unchanged from R1 — known correct)
// ---------------------------------------------------------------------------
__global__ __launch_bounds__(256) void gemm_phi(const float* __restrict__ A,
                                                const float* __restrict__ B,
                                                const float* __restrict__ bias,
                                                float* __restrict__ C) {
    __shared__ float As[16][68];
    __shared__ float Bs[16][68];
    const int tid = threadIdx.x;
    const int m0 = blockIdx.x * 64;
    const int n0 = blockIdx.y * 64;
    const int am = tid >> 2, ak = (tid & 3) << 2;
    const int bk = tid >> 4, bn = (tid & 15) << 2;
    const int ty = tid >> 4, tx = tid & 15;
    float acc[4][4] = {};
    for (int k0 = 0; k0 < K1; k0 += 16) {
        const float4 av = *(const float4*)&A[(size_t)(m0 + am) * K1 + k0 + ak];
        const float4 bv = *(const float4*)&B[(size_t)(k0 + bk) * N1 + n0 + bn];
        __syncthreads();
        As[ak + 0][am] = av.x; As[ak + 1][am] = av.y; As[ak + 2][am] = av.z; As[ak + 3][am] = av.w;
        *(float4*)&Bs[bk][bn] = bv;
        __syncthreads();
#pragma unroll
        for (int kk = 0; kk < 16; ++kk) {
            const float4 a = *(const float4*)&As[kk][ty << 2];
            const float4 b = *(const float4*)&Bs[kk][tx << 2];
            const float ar[4] = {a.x, a.y, a.z, a.w};
            const float br[4] = {b.x, b.y, b.z, b.w};
#pragma unroll
            for (int i = 0; i < 4; ++i)
#pragma unroll
                for (int j = 0; j < 4; ++j) acc[i][j] = fmaf(ar[i], br[j], acc[i][j]);
        }
    }
    const float4 bsv = *(const float4*)&bias[n0 + (tx << 2)];
    const float bb[4] = {bsv.x, bsv.y, bsv.z, bsv.w};
#pragma unroll
    for (int i = 0; i < 4; ++i) {
        const int m = m0 + (ty << 2) + i;
        float4 o;
        o.x = fmaxf(acc[i][0] + bb[0], 0.f);
        o.y = fmaxf(acc[i][1] + bb[1], 0.f);
        o.z = fmaxf(acc[i][2] + bb[2], 0.f);
        o.w = fmaxf(acc[i][3] + bb[3], 0.f);
        *(float4*)&C[(size_t)m * N1 + n0 + (tx << 2)] = o;
    }
}

// ---------------------------------------------------------------------------
// GEMM 2: gi0 = x_t @ Wih0^T + bih0  (unchanged from R1)
// ---------------------------------------------------------------------------
__global__ __launch_bounds__(256) void gemm_gi0(const float* __restrict__ xv,
                                                const float* __restrict__ Wih0,
                                                const float* __restrict__ bih0,
                                                float* __restrict__ C) {
    __shared__ float As[16][68];
    __shared__ float Bs[16][68];
    const int tid = threadIdx.x;
    const int m0 = blockIdx.x * 64;
    const int n0 = blockIdx.y * 64;
    const int am = tid >> 2, ak = (tid & 3) << 2;
    const int bn_ = tid >> 2, bkq = (tid & 3) << 2;
    const int ty = tid >> 4, tx = tid & 15;
    const int r = m0 + am;
    const int t = r / 30;
    const int j = r - t * 30;
    const float* rowTrk = xv + ((size_t)(t * 31 + 1 + j) << 9);
    const float* rowImg = xv + ((size_t)(t * 31) << 9);
    float acc[4][4] = {};
    for (int k0 = 0; k0 < K2; k0 += 16) {
        const int kg = k0 + ak;
        const float4 av = (kg < 512) ? *(const float4*)&rowTrk[kg]
                                     : *(const float4*)&rowImg[kg - 512];
        const float4 wv = *(const float4*)&Wih0[(size_t)(n0 + bn_) * K2 + k0 + bkq];
        __syncthreads();
        As[ak + 0][am] = av.x; As[ak + 1][am] = av.y; As[ak + 2][am] = av.z; As[ak + 3][am] = av.w;
        Bs[bkq + 0][bn_] = wv.x; Bs[bkq + 1][bn_] = wv.y; Bs[bkq + 2][bn_] = wv.z; Bs[bkq + 3][bn_] = wv.w;
        __syncthreads();
#pragma unroll
        for (int kk = 0; kk < 16; ++kk) {
            const float4 a = *(const float4*)&As[kk][ty << 2];
            const float4 b = *(const float4*)&Bs[kk][tx << 2];
            const float ar[4] = {a.x, a.y, a.z, a.w};
            const float br[4] = {b.x, b.y, b.z, b.w};
#pragma unroll
            for (int i = 0; i < 4; ++i)
#pragma unroll
                for (int jq = 0; jq < 4; ++jq) acc[i][jq] = fmaf(ar[i], br[jq], acc[i][jq]);
        }
    }
    const float4 bsv = *(const float4*)&bih0[n0 + (tx << 2)];
    const float bb[4] = {bsv.x, bsv.y, bsv.z, bsv.w};
#pragma unroll
    for (int i = 0; i < 4; ++i) {
        const int m = m0 + (ty << 2) + i;
        float4 o;
        o.x = acc[i][0] + bb[0];
        o.y = acc[i][1] + bb[1];
        o.z = acc[i][2] + bb[2];
        o.w = acc[i][3] + bb[3];
        *(float4*)&C[(size_t)m * N2 + n0 + (tx << 2)] = o;
    }
}

// ---------------------------------------------------------------------------
// gic = cor @ Wihc^T + bihc (unchanged)
// ---------------------------------------------------------------------------
__global__ __launch_bounds__(256) void gic_kernel(const int* __restrict__ y,
                                                  const float* __restrict__ Wihc,
                                                  const float* __restrict__ bihc,
                                                  float* __restrict__ gic) {
    const int idx = blockIdx.x * 256 + threadIdx.x;
    if (idx >= M2 * 96) return;
    const int g = idx % 96;
    const int tj = idx / 96;
    const int* yb = y + (size_t)tj * 6;
    const float c0 = (float)yb[1] * (1.f / 1080.f);
    const float c1 = (float)yb[2] * (1.f / 720.f);
    const float c2 = (float)yb[3] * (1.f / 1080.f);
    const float c3 = (float)yb[4] * (1.f / 720.f);
    gic[idx] = bihc[g] + c0 * Wihc[g * 4 + 0] + c1 * Wihc[g * 4 + 1]
                       + c2 * Wihc[g * 4 + 2] + c3 * Wihc[g * 4 + 3];
}

// W1T[u][c] = W1[c][u]  (one-time, lets classifier stream float4)
__global__ void transpose_w1(const float* __restrict__ W1, float* __restrict__ W1T) {
    const int idx = blockIdx.x * 256 + threadIdx.x;
    if (idx >= 544 * 256) return;
    const int c = idx % 544, u = idx / 544;
    W1T[idx] = W1[c * 256 + u];
}

__global__ void init_k(unsigned* cnt, unsigned* flag) {
    if (threadIdx.x == 0) { *cnt = 0u; *flag = 0u; }
}

// ---------------------------------------------------------------------------
// Grid barrier: agent-scope arrive + spin (256 WGs, all co-resident: 1024 waves)
// ---------------------------------------------------------------------------
__device__ __forceinline__ void gbar(unsigned* cnt, unsigned* flag, unsigned target) {
    __syncthreads();
    if (threadIdx.x == 0) {
        __threadfence();
        unsigned prev = __hip_atomic_fetch_add(cnt, 1u, __ATOMIC_ACQ_REL, __HIP_MEMORY_SCOPE_AGENT);
        if (prev + 1u == target * (unsigned)NWG) {
            __hip_atomic_store(flag, target, __ATOMIC_RELEASE, __HIP_MEMORY_SCOPE_AGENT);
        } else {
            while (__hip_atomic_load(flag, __ATOMIC_RELAXED, __HIP_MEMORY_SCOPE_AGENT) < target)
                __builtin_amdgcn_s_sleep(1);
        }
        __threadfence();
    }
    __syncthreads();
}

// masked softmax over 30 tracks (single thread; raw may be global or LDS)
__device__ void softmax30(const float* raw, const int* yt, float* outp) {
    float s[NBOX];
    float mx = -1e30f;
    for (int j = 0; j < NBOX; ++j) {
        s[j] = raw[j];
        if (yt[j * 6] != 0 && s[j] > mx) mx = s[j];
    }
    float sum = 0.f;
    for (int j = 0; j < NBOX; ++j) {
        s[j] = (yt[j * 6] != 0) ? __expf(s[j] - mx) : 0.f;
        sum += s[j];
    }
    const float inv = 1.f / fmaxf(sum, 1e-9f);
    for (int j = 0; j < NBOX; ++j) outp[j] = s[j] * inv;
}

struct PArgs {
    const float *gi0, *gic;
    const float *Whh0, *Wih1, *Whh1, *Whhc;
    const float *bhh0, *bih1, *bhh1, *bhhc;
    const float *W1T, *b1, *W2, *b2, *wa, *wac;
    const int *y;
    float *Z0, *Z1, *h0, *h1, *hc, *s0raw, *s1raw, *partials, *out;
    unsigned *cnt, *flag;
};

// ---------------------------------------------------------------------------
// Persistent scan kernel: 2 grid barriers / step.
// P(t): all WGs GEMV 6 Z0 cols + 2 gi1 col-triples on h0_n(t); fused h1-combine
//       (each WG owns (c,512+c,1024+c) so no extra sync); WGs224..253 s0 dots;
//       WG255 also runs the whole coord-GRU chain in persistent LDS.
// Q(t): WGs0..191 Z1 GEMV (8 cols); 192..223 classifier partials; 224..253 s1
//       dots; 254 classifier-finalize(t-1)+loss; ALL WGs h0-combine(t+1).
// ---------------------------------------------------------------------------
__global__ __launch_bounds__(256, 1) void persist(PArgs A) {
    __shared__ float gi_s[NBOX][6];
    __shared__ float sA[NBOX];
    __shared__ float red[256];
    __shared__ float chc[NBOX][32];   // WG255-only persistent coord state
    __shared__ float cZc[NBOX][96];
    __shared__ float cscr[NBOX];
    __shared__ float csca[NBOX];

    const int w = blockIdx.x;
    const int tid = threadIdx.x;
    unsigned ep = 0;
    float lossSum = 0.f;

    // ---- INIT: h0_n(0) (zero prev state -> s=0 path), parity 0
    if (tid < 60) {
        const int idx = w * 60 + tid;
        const int j = idx >> 9, c = idx & 511;
        const float* gp = A.gi0 + j * 1536;
        const float r = sigf(gp[c] + A.bhh0[c]);
        const float z = sigf(gp[512 + c] + A.bhh0[512 + c]);
        const float n = thf(gp[1024 + c] + r * A.bhh0[1024 + c]);
        A.h0[idx] = (1.f - z) * n;
    }
    gbar(A.cnt, A.flag, ++ep);

    for (int t = 0; t < TT; ++t) {
        const int parC = t & 1, parP = parC ^ 1;
        // ================= P(t) =================
        {
            const float* h0c = A.h0 + parC * 15360;   // h0_n(t)
            if (tid == 0) {
                if (t == 0) { for (int j = 0; j < NBOX; ++j) sA[j] = 0.f; }
                else softmax30(A.s1raw, A.y + (size_t)(t - 1) * 180, sA);
                if (w == NWG - 1) {
                    if (t == 0) { for (int j = 0; j < NBOX; ++j) csca[j] = 0.f; }
                    else softmax30(cscr, A.y + (size_t)(t - 1) * 180, csca);
                }
            }
            // prefetch h1-combine inputs (independent of this phase's GEMV)
            float z1r = 0.f, z1z = 0.f, z1n = 0.f, h1p = 0.f;
            int cj = 0, cc = 0;
            if (tid < 60) {
                cj = tid >> 1; cc = 2 * w + (tid & 1);
                z1r = A.Z1[cj * 1536 + cc];
                z1z = A.Z1[cj * 1536 + 512 + cc];
                z1n = A.Z1[cj * 1536 + 1024 + cc];
                h1p = A.h1[parP * 15360 + cj * 512 + cc];
            }
            // GEMV: 6 Whh0 cols + 6 Wih1 cols (2 triples)
            if (tid < 240 && (tid & 7) < 6) {
                const int j = tid >> 3, q = tid & 7;
                const float* hrow = h0c + j * 512;
                const float* W; int colA, colB;
                if (q < 3) { W = A.Whh0; colA = 6 * w + 2 * q; colB = colA + 1; }
                else {
                    W = A.Wih1;
                    const int G[6] = {2*w, 512 + 2*w, 1024 + 2*w, 2*w + 1, 513 + 2*w, 1025 + 2*w};
                    colA = G[(q - 3) * 2]; colB = G[(q - 3) * 2 + 1];
                }
                const float* wA = W + (size_t)colA * 512;
                const float* wB = W + (size_t)colB * 512;
                float a0 = 0.f, a1 = 0.f;
#pragma unroll 4
                for (int k = 0; k < 512; k += 4) {
                    const float4 h4 = ld4(hrow + k);
                    a0 += dot4(h4, ld4(wA + k));
                    a1 += dot4(h4, ld4(wB + k));
                }
                if (q < 3) { A.Z0[j * 1536 + colA] = a0; A.Z0[j * 1536 + colB] = a1; }
                else {
                    const int g = (q - 3) * 2;
                    gi_s[j][g]     = a0 + A.bih1[colA];
                    gi_s[j][g + 1] = a1 + A.bih1[colB];
                }
            }
            __syncthreads();
            // fused h1-combine: h1_n(t)
            if (tid < 60) {
                const float s = sA[cj];
                const int ci = tid & 1;
                const float r = sigf(gi_s[cj][ci * 3 + 0] + s * z1r + A.bhh1[cc]);
                const float z = sigf(gi_s[cj][ci * 3 + 1] + s * z1z + A.bhh1[512 + cc]);
                const float n = thf (gi_s[cj][ci * 3 + 2] + r * (s * z1n + A.bhh1[1024 + cc]));
                A.h1[parC * 15360 + cj * 512 + cc] = (1.f - z) * n + z * (s * h1p);
            }
            // s0 raw attention dots
            if (w >= 224 && w < 254) {
                const int jd = w - 224;
                const float* hrow = h0c + jd * 512;
                red[tid] = thf(hrow[tid]) * A.wa[tid] + thf(hrow[tid + 256]) * A.wa[tid + 256];
                __syncthreads();
                for (int sft = 128; sft > 0; sft >>= 1) {
                    if (tid < sft) red[tid] += red[tid + sft];
                    __syncthreads();
                }
                if (tid == 0) A.s0raw[jd] = red[0];
            }
            // coord-GRU chain (WG255, persistent LDS)
            if (w == NWG - 1) {
                for (int idx = tid; idx < 960; idx += 256) {
                    const int j = idx >> 5, c = idx & 31;
                    const float s = csca[j];
                    const float* gp = A.gic + (size_t)t * 2880 + j * 96;
                    const float r = sigf(gp[c]      + s * cZc[j][c]      + A.bhhc[c]);
                    const float z = sigf(gp[32 + c] + s * cZc[j][32 + c] + A.bhhc[32 + c]);
                    const float n = thf (gp[64 + c] + r * (s * cZc[j][64 + c] + A.bhhc[64 + c]));
                    const float hn = (1.f - z) * n + z * (s * chc[j][c]);
                    chc[j][c] = hn;
                    A.hc[j * 32 + c] = hn;
                }
                __syncthreads();
                for (int idx = tid; idx < 2880; idx += 256) {
                    const int j = idx / 96, g = idx - j * 96;
                    const float* wr = A.Whhc + g * 32;
                    float a = 0.f;
#pragma unroll
                    for (int c2 = 0; c2 < 32; c2 += 4) a += dot4(ld4(&chc[j][c2]), ld4(wr + c2));
                    cZc[j][g] = a;
                }
                if (tid < 240) {
                    const int j = tid >> 3, seg = tid & 7;
                    float p = 0.f;
                    for (int c2 = seg * 4; c2 < seg * 4 + 4; ++c2) p += thf(chc[j][c2]) * A.wac[c2];
                    p += __shfl_down(p, 4, 8);
                    p += __shfl_down(p, 2, 8);
                    p += __shfl_down(p, 1, 8);
                    if (seg == 0) cscr[j] = p;
                }
            }
        }
        gbar(A.cnt, A.flag, ++ep);
        // ================= Q(t) =================
        {
            const float* h1c = A.h1 + parC * 15360;   // h1_n(t)
            const float* h0c = A.h0 + parC * 15360;   // h0_n(t)
            if (tid == 0) softmax30(A.s0raw, A.y + (size_t)t * 180, sA);
            // prefetch h0-combine(t+1) inputs
            float g_r = 0.f, g_z = 0.f, g_n = 0.f, z0r = 0.f, z0z = 0.f, z0n = 0.f, h0p = 0.f;
            int cj2 = 0, cc2 = 0;
            if (tid < 60 && t < TT - 1) {
                const int idx = w * 60 + tid;
                cj2 = idx >> 9; cc2 = idx & 511;
                const float* gp = A.gi0 + (size_t)(t + 1) * 46080 + cj2 * 1536;
                g_r = gp[cc2]; g_z = gp[512 + cc2]; g_n = gp[1024 + cc2];
                z0r = A.Z0[cj2 * 1536 + cc2];
                z0z = A.Z0[cj2 * 1536 + 512 + cc2];
                z0n = A.Z0[cj2 * 1536 + 1024 + cc2];
                h0p = h0c[idx];
            }
            if (w < 192) {
                // Z1 GEMV: 8 cols
                if (tid < 240 && (tid & 7) < 4) {
                    const int j = tid >> 3, q = tid & 7;
                    const int colA = 8 * w + 2 * q, colB = colA + 1;
                    const float* hrow = h1c + j * 512;
                    const float* wA = A.Whh1 + (size_t)colA * 512;
                    const float* wB = A.Whh1 + (size_t)colB * 512;
                    float a0 = 0.f, a1 = 0.f;
#pragma unroll 4
                    for (int k = 0; k < 512; k += 4) {
                        const float4 h4 = ld4(hrow + k);
                        a0 += dot4(h4, ld4(wA + k));
                        a1 += dot4(h4, ld4(wB + k));
                    }
                    A.Z1[j * 1536 + colA] = a0;
                    A.Z1[j * 1536 + colB] = a1;
                }
            } else if (w < 224) {
                // classifier partials: 8 hidden units x 30 tracks
                const int b = w - 192;
                if (tid < 240) {
                    const int j = tid >> 3, u = tid & 7, ug = b * 8 + u;
                    const float* w1r = A.W1T + (size_t)ug * 544;
                    const float* hrow = h1c + j * 512;
                    float acc = A.b1[ug];
#pragma unroll 4
                    for (int c2 = 0; c2 < 512; c2 += 4) acc += dot4(ld4(hrow + c2), ld4(w1r + c2));
                    const float* hcr = A.hc + j * 32;
#pragma unroll
                    for (int c2 = 0; c2 < 32; c2 += 4) acc += dot4(ld4(hcr + c2), ld4(w1r + 512 + c2));
                    const float uu = fmaxf(acc, 0.f);
                    float p0 = uu * A.W2[2 * ug], p1 = uu * A.W2[2 * ug + 1];
                    p0 += __shfl_down(p0, 4, 8); p0 += __shfl_down(p0, 2, 8); p0 += __shfl_down(p0, 1, 8);
                    p1 += __shfl_down(p1, 4, 8); p1 += __shfl_down(p1, 2, 8); p1 += __shfl_down(p1, 1, 8);
                    if (u == 0) {
                        float* pp = A.partials + (t & 1) * 1920 + b * 60 + j * 2;
                        pp[0] = p0; pp[1] = p1;
                    }
                }
            } else if (w < 254) {
                // s1 raw attention dots
                const int jd = w - 224;
                const float* hrow = h1c + jd * 512;
                red[tid] = thf(hrow[tid]) * A.wa[tid] + thf(hrow[tid + 256]) * A.wa[tid + 256];
                __syncthreads();
                for (int sft = 128; sft > 0; sft >>= 1) {
                    if (tid < sft) red[tid] += red[tid + sft];
                    __syncthreads();
                }
                if (tid == 0) A.s1raw[jd] = red[0];
            } else if (w == 254 && t > 0) {
                // finalize classifier for t-1
                const int tt = t - 1, par = tt & 1;
                if (tid < 30) {
                    float o0 = A.b2[0], o1 = A.b2[1];
                    const float* pp = A.partials + par * 1920;
                    for (int b2i = 0; b2i < 32; ++b2i) {
                        o0 += pp[b2i * 60 + tid * 2];
                        o1 += pp[b2i * 60 + tid * 2 + 1];
                    }
                    const int* yb = A.y + (size_t)tt * 180 + tid * 6;
                    const float pm = (yb[0] != 0) ? 1.f : 0.f;
                    const float m = fmaxf(o0, o1);
                    const float lse = m + __logf(__expf(o0 - m) + __expf(o1 - m));
                    const float lt = (yb[5] == 0) ? o0 : o1;
                    red[tid] = pm * (lse - lt);
                    A.out[1 + (size_t)tt * 60 + tid * 2]     = o0 * pm;
                    A.out[1 + (size_t)tt * 60 + tid * 2 + 1] = o1 * pm;
                }
                __syncthreads();
                if (tid == 0) { float s = 0.f; for (int j = 0; j < NBOX; ++j) s += red[j]; lossSum += s; }
            }
            __syncthreads();
            // h0-combine(t+1)
            if (tid < 60 && t < TT - 1) {
                const float s = sA[cj2];
                const float r = sigf(g_r + s * z0r + A.bhh0[cc2]);
                const float z = sigf(g_z + s * z0z + A.bhh0[512 + cc2]);
                const float n = thf (g_n + r * (s * z0n + A.bhh0[1024 + cc2]));
                A.h0[parP * 15360 + cj2 * 512 + cc2] = (1.f - z) * n + z * (s * h0p);
            }
        }
        gbar(A.cnt, A.flag, ++ep);
    }
    // ---- epilogue: finalize t=511, write total loss
    if (w == 254) {
        const int tt = TT - 1, par = tt & 1;
        if (tid < 30) {
            float o0 = A.b2[0], o1 = A.b2[1];
            const float* pp = A.partials + par * 1920;
            for (int b2i = 0; b2i < 32; ++b2i) {
                o0 += pp[b2i * 60 + tid * 2];
                o1 += pp[b2i * 60 + tid * 2 + 1];
            }
            const int* yb = A.y + (size_t)tt * 180 + tid * 6;
            const float pm = (yb[0] != 0) ? 1.f : 0.f;
            const float m = fmaxf(o0, o1);
            const float lse = m + __logf(__expf(o0 - m) + __expf(o1 - m));
            const float lt = (yb[5] == 0) ? o0 : o1;
            red[tid] = pm * (lse - lt);
            A.out[1 + (size_t)tt * 60 + tid * 2]     = o0 * pm;
            A.out[1 + (size_t)tt * 60 + tid * 2 + 1] = o1 * pm;
        }
        __syncthreads();
        if (tid == 0) {
            float s = 0.f;
            for (int j = 0; j < NBOX; ++j) s += red[j];
            A.out[0] = lossSum + s;
        }
    }
}

// ---------------------------------------------------------------------------
extern "C" void kernel_launch(void* const* d_in, const int* in_sizes, int n_in,
                              void* d_out, int out_size, void* d_ws, size_t ws_size,
                              hipStream_t stream) {
    (void)in_sizes; (void)n_in; (void)out_size; (void)ws_size;
    const int*   y     = (const int*)d_in[1];
    const float* flow  = (const float*)d_in[2];
    const float* W_phi = (const float*)d_in[3];
    const float* b_phi = (const float*)d_in[4];
    const float* Wih0  = (const float*)d_in[5];
    const float* Whh0  = (const float*)d_in[6];
    const float* bih0  = (const float*)d_in[7];
    const float* bhh0  = (const float*)d_in[8];
    const float* Wih1  = (const float*)d_in[9];
    const float* Whh1  = (const float*)d_in[10];
    const float* bih1  = (const float*)d_in[11];
    const float* bhh1  = (const float*)d_in[12];
    const float* Whhc  = (const float*)d_in[14];
    const float* bihc  = (const float*)d_in[15];
    const float* bhhc  = (const float*)d_in[16];
    const float* Wihc  = (const float*)d_in[13];
    const float* W1    = (const float*)d_in[17];
    const float* b1    = (const float*)d_in[18];
    const float* W2    = (const float*)d_in[19];
    const float* b2    = (const float*)d_in[20];
    const float* wa    = (const float*)d_in[21];
    const float* wac   = (const float*)d_in[22];
    float* out = (float*)d_out;

    float* ws = (float*)d_ws;
    float* xv   = ws;  ws += (size_t)M1 * N1;
    float* gi0  = ws;  ws += (size_t)M2 * N2;
    float* gic  = ws;  ws += (size_t)M2 * 96;
    float* W1T  = ws;  ws += 544 * 256;
    float* Z0   = ws;  ws += NBOX * 1536;
    float* Z1   = ws;  ws += NBOX * 1536;
    float* h0   = ws;  ws += 2 * NBOX * 512;
    float* h1   = ws;  ws += 2 * NBOX * 512;
    float* hc   = ws;  ws += NBOX * 32;
    float* s0raw = ws; ws += 32;
    float* s1raw = ws; ws += 32;
    float* partials = ws; ws += 2 * 32 * NBOX * 2;
    unsigned* barmem = (unsigned*)ws; ws += 16;

    hipLaunchKernelGGL(init_k, dim3(1), dim3(64), 0, stream, barmem, barmem + 1);
    hipLaunchKernelGGL(gemm_phi, dim3(M1 / 64, N1 / 64), dim3(256), 0, stream, flow, W_phi, b_phi, xv);
    hipLaunchKernelGGL(gemm_gi0, dim3(M2 / 64, N2 / 64), dim3(256), 0, stream, xv, Wih0, bih0, gi0);
    hipLaunchKernelGGL(gic_kernel, dim3((M2 * 96 + 255) / 256), dim3(256), 0, stream, y, Wihc, bihc, gic);
    hipLaunchKernelGGL(transpose_w1, dim3((544 * 256 + 255) / 256), dim3(256), 0, stream, W1, W1T);

    PArgs A;
    A.gi0 = gi0; A.gic = gic;
    A.Whh0 = Whh0; A.Wih1 = Wih1; A.Whh1 = Whh1; A.Whhc = Whhc;
    A.bhh0 = bhh0; A.bih1 = bih1; A.bhh1 = bhh1; A.bhhc = bhhc;
    A.W1T = W1T; A.b1 = b1; A.W2 = W2; A.b2 = b2; A.wa = wa; A.wac = wac;
    A.y = y;
    A.Z0 = Z0; A.Z1 = Z1; A.h0 = h0; A.h1 = h1; A.hc = hc;
    A.s0raw = s0raw; A.s1raw = s1raw; A.partials = partials; A.out = out;
    A.cnt = barmem; A.flag = barmem + 1;
    hipLaunchKernelGGL(persist, dim3(NWG), dim3(256), 0, stream, A);
}